// Round 1
// baseline (576.744 us; speedup 1.0000x reference)
//
#include <hip/hip_runtime.h>

// Problem constants
#define SE_B   64
#define SE_C   384
#define SE_CH  96
#define SE_HW  3136   // 56*56
#define SE_HW4 784    // HW / 4

// Kernel 1: global average pool over spatial dims.
// One block per (b,c) row of 3136 contiguous floats.
__global__ __launch_bounds__(256) void se_pool_kernel(const float* __restrict__ x,
                                                      float* __restrict__ se) {
    const int row = blockIdx.x;  // b*C + c
    const float4* __restrict__ xr = (const float4*)(x + (size_t)row * SE_HW);
    float sum = 0.f;
    for (int i = threadIdx.x; i < SE_HW4; i += 256) {
        float4 v = xr[i];
        sum += (v.x + v.y) + (v.z + v.w);
    }
    // wave64 reduce
    #pragma unroll
    for (int off = 32; off > 0; off >>= 1) sum += __shfl_down(sum, off, 64);
    __shared__ float wsum[4];
    const int lane = threadIdx.x & 63;
    const int wid  = threadIdx.x >> 6;
    if (lane == 0) wsum[wid] = sum;
    __syncthreads();
    if (threadIdx.x == 0) {
        float s = (wsum[0] + wsum[1]) + (wsum[2] + wsum[3]);
        se[row] = s * (1.0f / SE_HW);
    }
}

// Kernel 2: tiny 2-layer MLP + sigmoid -> gate[B*C].
// One block per batch element, 384 threads.
__global__ __launch_bounds__(384) void se_mlp_kernel(const float* __restrict__ se,
                                                     const float* __restrict__ w_reduce,
                                                     const float* __restrict__ b_reduce,
                                                     const float* __restrict__ w_expand,
                                                     const float* __restrict__ b_expand,
                                                     float* __restrict__ gate) {
    const int b = blockIdx.x;
    __shared__ float se_s[SE_C];
    __shared__ float h_s[SE_CH];
    const int tid = threadIdx.x;

    se_s[tid] = se[b * SE_C + tid];
    __syncthreads();

    if (tid < SE_CH) {
        float acc = b_reduce[tid];
        const float* __restrict__ w = w_reduce + tid * SE_C;
        #pragma unroll 4
        for (int c = 0; c < SE_C; ++c) acc = fmaf(w[c], se_s[c], acc);
        h_s[tid] = fmaxf(acc, 0.f);
    }
    __syncthreads();

    {
        float acc = b_expand[tid];
        const float* __restrict__ w = w_expand + tid * SE_CH;
        #pragma unroll 4
        for (int h = 0; h < SE_CH; ++h) acc = fmaf(w[h], h_s[h], acc);
        gate[b * SE_C + tid] = 1.0f / (1.0f + __expf(-acc));
    }
}

// Kernel 3: out = sigmoid-gate broadcast multiply.
// One block per (b,c) row; scalar gate, float4 traffic.
__global__ __launch_bounds__(256) void se_scale_kernel(const float* __restrict__ x,
                                                       const float* __restrict__ gate,
                                                       float* __restrict__ out) {
    const int row = blockIdx.x;  // b*C + c
    const float g = gate[row];
    const float4* __restrict__ xr = (const float4*)(x + (size_t)row * SE_HW);
    float4* __restrict__ orow = (float4*)(out + (size_t)row * SE_HW);
    for (int i = threadIdx.x; i < SE_HW4; i += 256) {
        float4 v = xr[i];
        v.x *= g; v.y *= g; v.z *= g; v.w *= g;
        orow[i] = v;
    }
}

extern "C" void kernel_launch(void* const* d_in, const int* in_sizes, int n_in,
                              void* d_out, int out_size, void* d_ws, size_t ws_size,
                              hipStream_t stream) {
    const float* x        = (const float*)d_in[0];
    const float* w_reduce = (const float*)d_in[1];
    const float* b_reduce = (const float*)d_in[2];
    const float* w_expand = (const float*)d_in[3];
    const float* b_expand = (const float*)d_in[4];
    float* out = (float*)d_out;

    float* se   = (float*)d_ws;            // B*C floats
    float* gate = se + SE_B * SE_C;        // B*C floats

    se_pool_kernel<<<SE_B * SE_C, 256, 0, stream>>>(x, se);
    se_mlp_kernel<<<SE_B, SE_C, 0, stream>>>(se, w_reduce, b_reduce,
                                             w_expand, b_expand, gate);
    se_scale_kernel<<<SE_B * SE_C, 256, 0, stream>>>(x, gate, out);
}

// Round 2
// 568.194 us; speedup vs baseline: 1.0150x; 1.0150x over previous
//
#include <hip/hip_runtime.h>

// Problem constants
#define SE_B   64
#define SE_C   384
#define SE_CH  96
#define SE_HW  3136   // 56*56
#define SE_HW4 784    // HW / 4
#define SE_ROWS (SE_B * SE_C)   // 24576
#define SE_BLOCKS (SE_ROWS / 4) // 6144, one wave per row, 4 waves/block

typedef float floatx4 __attribute__((ext_vector_type(4)));

// Kernel 1: global average pool. One wave (64 lanes) per (b,c) row.
__global__ __launch_bounds__(256) void se_pool_kernel(const float* __restrict__ x,
                                                      float* __restrict__ se) {
    const int wave = threadIdx.x >> 6;
    const int lane = threadIdx.x & 63;
    const int row  = blockIdx.x * 4 + wave;   // b*C + c
    const floatx4* __restrict__ xr = (const floatx4*)(x + (size_t)row * SE_HW);
    float sum = 0.f;
    for (int i = lane; i < SE_HW4; i += 64) {  // 784 = 12*64 + 16
        floatx4 v = xr[i];
        sum += (v.x + v.y) + (v.z + v.w);
    }
    #pragma unroll
    for (int off = 32; off > 0; off >>= 1) sum += __shfl_down(sum, off, 64);
    if (lane == 0) se[row] = sum * (1.0f / SE_HW);
}

// Kernel 2: tiny 2-layer MLP + sigmoid -> gate[B*C]. One block per batch.
__global__ __launch_bounds__(384) void se_mlp_kernel(const float* __restrict__ se,
                                                     const float* __restrict__ w_reduce,
                                                     const float* __restrict__ b_reduce,
                                                     const float* __restrict__ w_expand,
                                                     const float* __restrict__ b_expand,
                                                     float* __restrict__ gate) {
    const int b = blockIdx.x;
    __shared__ float se_s[SE_C];
    __shared__ float h_s[SE_CH];
    const int tid = threadIdx.x;

    se_s[tid] = se[b * SE_C + tid];
    __syncthreads();

    if (tid < SE_CH) {
        float acc = b_reduce[tid];
        const float* __restrict__ w = w_reduce + tid * SE_C;
        #pragma unroll 4
        for (int c = 0; c < SE_C; ++c) acc = fmaf(w[c], se_s[c], acc);
        h_s[tid] = fmaxf(acc, 0.f);
    }
    __syncthreads();

    {
        float acc = b_expand[tid];
        const float* __restrict__ w = w_expand + tid * SE_CH;
        #pragma unroll 4
        for (int h = 0; h < SE_CH; ++h) acc = fmaf(w[h], h_s[h], acc);
        gate[b * SE_C + tid] = 1.0f / (1.0f + __expf(-acc));
    }
}

// Kernel 3: out = gate * x. One wave per row; REVERSE block order so the
// earliest scale blocks read the rows pool touched last (still L3-resident).
// Nontemporal loads (hit-but-don't-pollute) and stores (don't evict x).
__global__ __launch_bounds__(256) void se_scale_kernel(const float* __restrict__ x,
                                                       const float* __restrict__ gate,
                                                       float* __restrict__ out) {
    const int wave = threadIdx.x >> 6;
    const int lane = threadIdx.x & 63;
    const int row  = (SE_BLOCKS - 1 - blockIdx.x) * 4 + wave;
    const float g = gate[row];
    const floatx4* __restrict__ xr   = (const floatx4*)(x + (size_t)row * SE_HW);
    floatx4* __restrict__       orow = (floatx4*)(out + (size_t)row * SE_HW);
    for (int i = lane; i < SE_HW4; i += 64) {
        floatx4 v = __builtin_nontemporal_load(&xr[i]);
        v *= g;
        __builtin_nontemporal_store(v, &orow[i]);
    }
}

extern "C" void kernel_launch(void* const* d_in, const int* in_sizes, int n_in,
                              void* d_out, int out_size, void* d_ws, size_t ws_size,
                              hipStream_t stream) {
    const float* x        = (const float*)d_in[0];
    const float* w_reduce = (const float*)d_in[1];
    const float* b_reduce = (const float*)d_in[2];
    const float* w_expand = (const float*)d_in[3];
    const float* b_expand = (const float*)d_in[4];
    float* out = (float*)d_out;

    float* se   = (float*)d_ws;            // B*C floats
    float* gate = se + SE_ROWS;            // B*C floats

    se_pool_kernel<<<SE_BLOCKS, 256, 0, stream>>>(x, se);
    se_mlp_kernel<<<SE_B, SE_C, 0, stream>>>(se, w_reduce, b_reduce,
                                             w_expand, b_expand, gate);
    se_scale_kernel<<<SE_BLOCKS, 256, 0, stream>>>(x, gate, out);
}